// Round 8
// baseline (218.621 us; speedup 1.0000x reference)
//
#include <hip/hip_runtime.h>
#include <math.h>

// NetVLAD fused forward, MI355X. fp16-compensated MFMA, transposed-logits.
// B=64, L=4096, D=128, K=64.
#define NB 64
#define NL 4096
#define ND 128
#define NK 64
#define NS 8            // slices per batch item (grid = NB*NS = 512 blocks)
#define LC (NL / NS)    // 512 rows per block
#define LT 64           // rows per tile
#define NT (LC / LT)    // 8 tiles per block

typedef _Float16 h8 __attribute__((ext_vector_type(8)));
typedef _Float16 h4 __attribute__((ext_vector_type(4)));
typedef float f4 __attribute__((ext_vector_type(4)));

#define MFMA16(A, B, C) __builtin_amdgcn_mfma_f32_16x16x32_f16(A, B, C, 0, 0, 0)
#define QSCALE 2048.0f
#define QINV   4.8828125e-4f   // 2^-11

// W[k][d] 64x128 f16: slot(d>>3, 16/row) XOR (k&15); frag reads conflict-free
__device__ __forceinline__ int w_idx(int k, int d) {
    return k * 128 + ((((d >> 3) ^ (k & 15)) & 15) << 3) + (d & 7);
}
// xT[d][c] 128x64 f16: slot(c>>3, 8/row) XOR (d&7)^((d>>3)&7)
__device__ __forceinline__ int xt_idx(int d, int c) {
    return d * 64 + ((((c >> 3) ^ (d & 7) ^ ((d >> 3) & 7)) & 7) << 3) + (c & 7);
}

// ---------------------------------------------------------------------------
// Kernel A. Per tile: x rows in regs (lane = its frag rows), L2-norm, f16
// hi/lo split; logits = mfma(W, x) -> lane holds 16 k of ONE row: in-reg
// softmax (4 shuffles); pooling = mfma(aT, xT) 2-term compensated.
// LDS = Wh16K + Wl16K + xTh16K + aTh8K + aTl8K = 64 KiB -> 2 blocks/CU.
// ---------------------------------------------------------------------------
__global__ __launch_bounds__(256, 2)
void vlad_partial_kernel(const float* __restrict__ x,
                         const float* __restrict__ Wg,   // assign_w [K][D]
                         const float* __restrict__ bg,   // assign_b [K]
                         float* __restrict__ wsv,        // [B][S][K][D] partials
                         float* __restrict__ wsa)        // [B][S][K] partial asum
{
    __shared__ __attribute__((aligned(16))) _Float16 sm[32768];  // 64 KiB
    _Float16* Wh  = sm;            // 8192 = 64x128
    _Float16* Wl  = sm + 8192;
    _Float16* xTh = sm + 16384;    // 8192 = 128x64
    _Float16* aTh = sm + 24576;    // 4096 = 64x64
    _Float16* aTl = sm + 28672;

    const int tid = threadIdx.x;
    const int b = blockIdx.x / NS;
    const int s = blockIdx.x % NS;
    const int l   = tid & 63;     // lane
    const int w   = tid >> 6;     // wave 0..3
    const int l15 = l & 15;
    const int wl4 = l >> 4;       // 0..3

    const float* xb = x + ((size_t)b * NL + (size_t)s * LC) * ND;

    // ---- stage W as f16 hi + scaled lo (packed h4 writes) ----
    {
        const int k  = tid & 63;
        const int d0 = (tid >> 6) * 32;
        const float4* wr = (const float4*)(Wg + k * ND + d0);
#pragma unroll
        for (int i = 0; i < 8; ++i) {
            float4 wv = wr[i];
            float vv[4] = {wv.x, wv.y, wv.z, wv.w};
            h4 whi, wlo;
#pragma unroll
            for (int j = 0; j < 4; ++j) {
                const _Float16 h = (_Float16)vv[j];
                whi[j] = h;
                wlo[j] = (_Float16)((vv[j] - (float)h) * QSCALE);
            }
            const int id = w_idx(k, d0 + 4 * i);   // (d&7) in {0,4}: 8B aligned
            *(h4*)(Wh + id) = whi;
            *(h4*)(Wl + id) = wlo;
        }
    }

    // bias for lane's 16 k-values: k = 16kt + 4wl4 + r
    float4 bias4[4];
#pragma unroll
    for (int kt = 0; kt < 4; ++kt)
        bias4[kt] = *(const float4*)(bg + 16 * kt + 4 * wl4);

    const f4 fzero = {0.f, 0.f, 0.f, 0.f};
    f4 P[4][2], Q[4][2];
#pragma unroll
    for (int i = 0; i < 4; ++i)
#pragma unroll
        for (int j = 0; j < 2; ++j) { P[i][j] = fzero; Q[i][j] = fzero; }

    float asum16[16];
#pragma unroll
    for (int i = 0; i < 16; ++i) asum16[i] = 0.f;

    // ---- prefetch tile 0: lane owns row 16w+l15, d-chunks 8*wl4 + 32*kk ----
    float4 va[4], vb4[4];
    {
        const float* gp = xb + (size_t)(16 * w + l15) * ND + 8 * wl4;
#pragma unroll
        for (int kk = 0; kk < 4; ++kk) {
            va[kk]  = *(const float4*)(gp + 32 * kk);
            vb4[kk] = *(const float4*)(gp + 32 * kk + 4);
        }
    }

    const int cRow = 16 * w + l15;   // this lane's tile-row (= aT/xT column)

    for (int t = 0; t < NT; ++t) {
        // ---- row L2 norm (4 lanes share a row across wl4) ----
        float ss = 0.f;
#pragma unroll
        for (int kk = 0; kk < 4; ++kk) {
            ss += va[kk].x * va[kk].x + va[kk].y * va[kk].y +
                  va[kk].z * va[kk].z + va[kk].w * va[kk].w;
            ss += vb4[kk].x * vb4[kk].x + vb4[kk].y * vb4[kk].y +
                  vb4[kk].z * vb4[kk].z + vb4[kk].w * vb4[kk].w;
        }
        ss += __shfl_xor(ss, 16);
        ss += __shfl_xor(ss, 32);
        const float sc = 1.f / fmaxf(sqrtf(ss), 1e-12f);

        // ---- fp16 hi/lo split in registers ----
        h8 xh[4], xl[4];
#pragma unroll
        for (int kk = 0; kk < 4; ++kk) {
            float f[8] = {va[kk].x * sc, va[kk].y * sc, va[kk].z * sc, va[kk].w * sc,
                          vb4[kk].x * sc, vb4[kk].y * sc, vb4[kk].z * sc, vb4[kk].w * sc};
#pragma unroll
            for (int e = 0; e < 8; ++e) {
                const _Float16 h = (_Float16)f[e];
                xh[kk][e] = h;
                xl[kk][e] = (_Float16)((f[e] - (float)h) * QSCALE);
            }
        }

        __syncthreads();   // prev tile's pooling done reading xT/aT (t=0: W ready)

        // ---- write xT hi (transposed copy for pooling B-frags; b16 stores) ----
#pragma unroll
        for (int kk = 0; kk < 4; ++kk)
#pragma unroll
            for (int e = 0; e < 8; ++e) {
                const int d = 32 * kk + 8 * wl4 + e;
                xTh[xt_idx(d, cRow)] = xh[kk][e];
            }

        // ---- prefetch next tile (hides under logits+softmax+pooling) ----
        if (t + 1 < NT) {
            const float* gp = xb + (size_t)((t + 1) * LT + 16 * w + l15) * ND + 8 * wl4;
#pragma unroll
            for (int kk = 0; kk < 4; ++kk) {
                va[kk]  = *(const float4*)(gp + 32 * kk);
                vb4[kk] = *(const float4*)(gp + 32 * kk + 4);
            }
        }

        // ---- logits (TRANSPOSED): D[k][row]; lane holds k=16kt+4wl4+r, row=cRow
        f4 aP[4], aQ[4];
#pragma unroll
        for (int kt = 0; kt < 4; ++kt) { aP[kt] = fzero; aQ[kt] = fzero; }
#pragma unroll
        for (int kk = 0; kk < 4; ++kk) {
#pragma unroll
            for (int kt = 0; kt < 4; ++kt) {
                const int k    = 16 * kt + l15;
                const int base = k * 128 + ((((4 * kk + wl4) ^ (k & 15)) & 15) << 3);
                const h8 wh = *(const h8*)(Wh + base);
                const h8 wl = *(const h8*)(Wl + base);
                aP[kt] = MFMA16(wh, xh[kk], aP[kt]);   // A=W, B=x (swapped)
                aQ[kt] = MFMA16(wl, xh[kk], aQ[kt]);
                aQ[kt] = MFMA16(wh, xl[kk], aQ[kt]);
            }
        }

        // ---- in-register softmax over 16 k + 2+2 shuffles across wl4 ----
        float Lg[16];
#pragma unroll
        for (int kt = 0; kt < 4; ++kt)
#pragma unroll
            for (int r = 0; r < 4; ++r)
                Lg[4 * kt + r] = aP[kt][r] + aQ[kt][r] * QINV +
                                 ((const float*)&bias4[kt])[r];

        float mx = fmaxf(Lg[0], Lg[1]);
#pragma unroll
        for (int i = 2; i < 16; ++i) mx = fmaxf(mx, Lg[i]);
        mx = fmaxf(mx, __shfl_xor(mx, 16));
        mx = fmaxf(mx, __shfl_xor(mx, 32));

        float ee[16];
        float sum = 0.f;
#pragma unroll
        for (int i = 0; i < 16; ++i) { ee[i] = __expf(Lg[i] - mx); sum += ee[i]; }
        sum += __shfl_xor(sum, 16);
        sum += __shfl_xor(sum, 32);
        const float inv = 1.f / sum;

        // ---- write aT (scalar b16, slot-XOR swizzle); accumulate asum ----
#pragma unroll
        for (int kt = 0; kt < 4; ++kt)
#pragma unroll
            for (int r = 0; r < 4; ++r) {
                const float a = ee[4 * kt + r] * inv;
                asum16[4 * kt + r] += a;
                const int k  = 16 * kt + 4 * wl4 + r;
                const int id = k * 64 + ((((cRow >> 3) ^ (k & 7)) & 7) << 3) + (cRow & 7);
                const _Float16 h = (_Float16)a;
                aTh[id] = h;
                aTl[id] = (_Float16)((a - (float)h) * QSCALE);
            }

        __syncthreads();   // xT + aT ready

        // ---- pooling: wave owns d-band [32w,32w+32); all 64 k; 2-term ----
#pragma unroll
        for (int st = 0; st < 2; ++st) {
            const int c0 = 32 * st + 8 * wl4;
            h8 ah[4], al[4];
#pragma unroll
            for (int kt = 0; kt < 4; ++kt) {
                const int k    = 16 * kt + l15;
                const int base = k * 64 + ((((c0 >> 3) ^ (k & 7)) & 7) << 3);
                ah[kt] = *(const h8*)(aTh + base);
                al[kt] = *(const h8*)(aTl + base);
            }
#pragma unroll
            for (int dt = 0; dt < 2; ++dt) {
                const int d    = 32 * w + 16 * dt + l15;
                const int base = d * 64 + ((((c0 >> 3) ^ (d & 7) ^ ((d >> 3) & 7)) & 7) << 3);
                const h8 bh = *(const h8*)(xTh + base);
#pragma unroll
                for (int kt = 0; kt < 4; ++kt) {
                    P[kt][dt] = MFMA16(ah[kt], bh, P[kt][dt]);
                    Q[kt][dt] = MFMA16(al[kt], bh, Q[kt][dt]);
                }
            }
        }
    }

    // ---- write partial vlad (merge compensated accumulators) ----
    float* ob = wsv + (size_t)(b * NS + s) * NK * ND;
#pragma unroll
    for (int kt = 0; kt < 4; ++kt)
#pragma unroll
        for (int dt = 0; dt < 2; ++dt)
#pragma unroll
            for (int r = 0; r < 4; ++r) {
                const int k = 16 * kt + 4 * wl4 + r;
                const int d = 32 * w + 16 * dt + l15;
                ob[k * ND + d] = P[kt][dt][r] + Q[kt][dt][r] * QINV;
            }

    // ---- asum: reduce over this wave's 16 rows (l15), cross-wave via LDS ----
#pragma unroll
    for (int i = 0; i < 16; ++i) {
        float vv = asum16[i];
        vv += __shfl_xor(vv, 1);
        vv += __shfl_xor(vv, 2);
        vv += __shfl_xor(vv, 4);
        vv += __shfl_xor(vv, 8);
        asum16[i] = vv;
    }
    __syncthreads();               // everyone past last pooling; W region free
    float* scr = (float*)sm;
    if (l15 == 0) {                // one lane per wl4 group holds the sums
#pragma unroll
        for (int kt = 0; kt < 4; ++kt)
#pragma unroll
            for (int r = 0; r < 4; ++r)
                scr[w * 64 + 16 * kt + 4 * wl4 + r] = asum16[4 * kt + r];
    }
    __syncthreads();
    if (tid < NK) {
        wsa[(size_t)(b * NS + s) * NK + tid] =
            scr[tid] + scr[64 + tid] + scr[128 + tid] + scr[192 + tid];
    }
}

// ---------------------------------------------------------------------------
// Kernel B: reduce NS partials, subtract asum*centroid, intra-cluster L2
// normalize, BatchNorm (inference), write output. One wave per (b,k).
// ---------------------------------------------------------------------------
__global__ __launch_bounds__(64)
void vlad_finalize_kernel(const float* __restrict__ wsv,
                          const float* __restrict__ wsa,
                          const float* __restrict__ cen,
                          const float* __restrict__ gam,
                          const float* __restrict__ bet,
                          const float* __restrict__ mu,
                          const float* __restrict__ var,
                          float* __restrict__ out)
{
    const int bk = blockIdx.x;
    const int b = bk >> 6;
    const int k = bk & 63;
    const int lane = threadIdx.x;

    const float* vb = wsv + (size_t)b * NS * NK * ND + (size_t)k * ND;
    float v0 = 0.f, v1 = 0.f, as = 0.f;
#pragma unroll
    for (int s = 0; s < NS; ++s) {
        const float* p = vb + (size_t)s * NK * ND;
        v0 += p[lane];
        v1 += p[lane + 64];
        as += wsa[(b * NS + s) * NK + k];
    }
    const int i0 = k * ND + lane;
    const int i1 = i0 + 64;
    v0 -= as * cen[i0];
    v1 -= as * cen[i1];

    float ss = v0 * v0 + v1 * v1;
#pragma unroll
    for (int o = 1; o < 64; o <<= 1) ss += __shfl_xor(ss, o);
    const float sc = 1.f / fmaxf(sqrtf(ss), 1e-12f);

    const float n0 = v0 * sc;
    const float n1 = v1 * sc;
    float* ob = out + (size_t)b * NK * ND;
    ob[i0] = gam[i0] * (n0 - mu[i0]) * rsqrtf(var[i0] + 1e-5f) + bet[i0];
    ob[i1] = gam[i1] * (n1 - mu[i1]) * rsqrtf(var[i1] + 1e-5f) + bet[i1];
}

extern "C" void kernel_launch(void* const* d_in, const int* in_sizes, int n_in,
                              void* d_out, int out_size, void* d_ws, size_t ws_size,
                              hipStream_t stream) {
    const float* x  = (const float*)d_in[0];
    const float* aw = (const float*)d_in[1];
    const float* ab = (const float*)d_in[2];
    const float* ce = (const float*)d_in[3];
    const float* g  = (const float*)d_in[4];
    const float* be = (const float*)d_in[5];
    const float* mu = (const float*)d_in[6];
    const float* va = (const float*)d_in[7];
    float* out = (float*)d_out;

    float* wsv = (float*)d_ws;                              // B*S*K*D floats (16 MiB)
    float* wsa = wsv + (size_t)NB * NS * NK * ND;           // B*S*K floats (128 KiB)

    hipLaunchKernelGGL(vlad_partial_kernel, dim3(NB * NS), dim3(256), 0, stream,
                       x, aw, ab, wsv, wsa);
    hipLaunchKernelGGL(vlad_finalize_kernel, dim3(NB * NK), dim3(64), 0, stream,
                       wsv, wsa, ce, g, be, mu, va, out);
}